// Round 3
// baseline (83161.212 us; speedup 1.0000x reference)
//
#include <hip/hip_runtime.h>
#include <stdint.h>

// Problem constants
#define NB 256      // batch
#define NS 512      // seq
#define NV 32       // vocab
#define NE 128      // embed
#define NH 512      // rnn units
#define N4H 2048    // 4*H

typedef __attribute__((ext_vector_type(8))) short short8;
typedef __attribute__((ext_vector_type(4))) float f32x4;
typedef __attribute__((ext_vector_type(4))) unsigned int u32x4;
typedef __attribute__((ext_vector_type(4))) unsigned short u16x4;

__device__ __forceinline__ float bf2f(unsigned short u){
  unsigned int x = ((unsigned int)u) << 16;
  return __builtin_bit_cast(float, x);
}
__device__ __forceinline__ unsigned short f2bf(float f){
  unsigned int u = __builtin_bit_cast(unsigned int, f);
  u += 0x7fffu + ((u >> 16) & 1u);
  return (unsigned short)(u >> 16);
}
// async global->LDS, 16B per lane; LDS dest = wave-uniform base + lane*16
__device__ __forceinline__ void gload_lds16(const void* g, void* l){
  __builtin_amdgcn_global_load_lds(
      (const __attribute__((address_space(1))) unsigned int*)(uintptr_t)g,
      (__attribute__((address_space(3))) unsigned int*)(uintptr_t)l,
      16, 0, 0);
}

// ---------------------------------------------------------------------------
// Transpose + cast f32 [K][N] -> bf16 [N][K]
// ---------------------------------------------------------------------------
__global__ __launch_bounds__(256) void transpose_cast(
    const float* __restrict__ in, unsigned short* __restrict__ out, int K, int N)
{
  int k = blockIdx.x * 256 + threadIdx.x;
  int n = blockIdx.y;
  if (k < K) out[(long)n * K + k] = f2bf(in[(long)k * N + n]);
}

// ---------------------------------------------------------------------------
// Embedding (time-major): x0[t][b][e] = bf16(emb[tok[b][t]][e] * sqrt(128))
// ---------------------------------------------------------------------------
__global__ __launch_bounds__(256) void embed_kernel(
    const int* __restrict__ tok, const float* __restrict__ emb,
    unsigned short* __restrict__ x0)
{
  long gid = (long)blockIdx.x * 256 + threadIdx.x;
  long idx = gid * 4;                     // element index into [NS][NB][NE]
  int e = (int)(idx & 127);
  int b = (int)((idx >> 7) & 255);
  int t = (int)(idx >> 15);
  int tk = tok[b * NS + t];
  f32x4 v = *(const f32x4*)(emb + (long)tk * NE + e);
  u16x4 o;
  #pragma unroll
  for (int i = 0; i < 4; ++i) o[i] = f2bf(v[i] * 11.313708498984761f);
  *(u16x4*)(x0 + idx) = o;
}

// ---------------------------------------------------------------------------
// GEMM: C[M][N] = A[M][K] * BT[N][K]^T  (+bias, +relu, f32/bf16 out, row remap)
// m97-style: 256 thr, BK=64, global_load_lds staging, 16x16x32 bf16 MFMA
// ---------------------------------------------------------------------------
template<int BM, int BN, bool BIAS, bool RELU, bool F32OUT, bool REMAP>
__global__ __launch_bounds__(256) void gemm_bt(
    const unsigned short* __restrict__ A, const unsigned short* __restrict__ BT,
    void* __restrict__ Cv, const float* __restrict__ bias,
    int M, int N, int K, int rowoff)
{
  constexpr int BK = 64;
  constexpr int WN = (BN >= 64) ? 2 : 1;
  constexpr int WM = 4 / WN;
  constexpr int WTM = BM / WM, WTN = BN / WN;
  constexpr int FM = WTM / 16, FN = WTN / 16;
  __shared__ unsigned short lds[(BM + BN) * BK];
  unsigned short* As = lds;
  unsigned short* Bs = lds + BM * BK;
  const int tid = threadIdx.x;
  const int w = tid >> 6, l = tid & 63;
  const int n0 = blockIdx.x * BN, m0 = blockIdx.y * BM;
  const int wm = (WN == 2) ? (w >> 1) : w;
  const int wn = (WN == 2) ? (w & 1) : 0;

  f32x4 acc[FM][FN];
  #pragma unroll
  for (int i = 0; i < FM; i++)
    #pragma unroll
    for (int j = 0; j < FN; j++) acc[i][j] = (f32x4)0.f;

  constexpr int CH_A = BM * 8;            // 16B chunks in A region
  constexpr int CH_T = (BM + BN) * 8;
  constexpr int PW = CH_T / 4;
  static_assert(PW % 64 == 0, "staging alignment");
  static_assert(CH_A % 64 == 0, "region boundary alignment");

  for (int kt = 0; kt < K; kt += BK) {
    #pragma unroll
    for (int i = 0; i < PW / 64; ++i) {
      int c0 = w * PW + i * 64;           // wave-uniform
      int c = c0 + l;
      const unsigned short* g;
      if (c0 < CH_A) {
        int row = c >> 3, col = c & 7;
        g = A + (long)(m0 + row) * K + kt + col * 8;
      } else {
        int cb = c - CH_A;
        int row = cb >> 3, col = cb & 7;
        g = BT + (long)(n0 + row) * K + kt + col * 8;
      }
      gload_lds16(g, lds + (size_t)c0 * 8);
    }
    __syncthreads();
    #pragma unroll
    for (int ks = 0; ks < BK / 32; ++ks) {
      short8 a[FM], b[FN];
      #pragma unroll
      for (int mt = 0; mt < FM; ++mt)
        a[mt] = *(const short8*)&As[(wm * WTM + mt * 16 + (l & 15)) * BK + ks * 32 + (l >> 4) * 8];
      #pragma unroll
      for (int nt = 0; nt < FN; ++nt)
        b[nt] = *(const short8*)&Bs[(wn * WTN + nt * 16 + (l & 15)) * BK + ks * 32 + (l >> 4) * 8];
      #pragma unroll
      for (int mt = 0; mt < FM; ++mt)
        #pragma unroll
        for (int nt = 0; nt < FN; ++nt)
          acc[mt][nt] = __builtin_amdgcn_mfma_f32_16x16x32_bf16(a[mt], b[nt], acc[mt][nt], 0, 0, 0);
    }
    __syncthreads();
  }

  const int row_l = l >> 4, col_l = l & 15;
  #pragma unroll
  for (int nt = 0; nt < FN; ++nt) {
    int col = n0 + wn * WTN + nt * 16 + col_l;
    float bv = 0.f;
    if (BIAS) bv = bias[col];
    #pragma unroll
    for (int mt = 0; mt < FM; ++mt) {
      #pragma unroll
      for (int i = 0; i < 4; ++i) {
        int m = m0 + wm * WTM + mt * 16 + row_l * 4 + i;
        float v = acc[mt][nt][i] + bv;
        if (RELU) v = v > 0.f ? v : 0.f;
        long cidx;
        if (REMAP) {
          int gr = rowoff + m;            // global time-major row = t*NB + b
          int b_ = gr & (NB - 1), t_ = gr >> 8;
          cidx = ((long)b_ * NS + t_) * N + col;
        } else {
          cidx = (long)m * N + col;
        }
        if (F32OUT) ((float*)Cv)[cidx] = v;
        else ((unsigned short*)Cv)[cidx] = f2bf(v);
      }
    }
  }
}

// ---------------------------------------------------------------------------
// LSTM scan chunk: persistent 256-WG kernel (regular launch; 1 block/CU via
// LDS). 8 batch-groups x 32 unit-slice WGs. WG owns 16 hidden units (64 gate
// cols) for 32 batch rows; U-slice resident in LDS. Per step: acquire flag,
// stage h (32KB), z = h@U via MFMA, LDS gate exchange, fp32 gates, write h +
// release flag. Bounded spins: co-residency failure -> wrong answer, not hang.
// ---------------------------------------------------------------------------
#define SC_LDS_U 65536            // 16ks x 4gate x 64lane x 16B (frag-linear)
#define SC_LDS_H (16 * 32 * 80)   // [16 ks][32 r][80B: 64B data + 16B pad]
#define SC_LDS_Z (32 * 65 * 4)    // z exchange [32][65] f32
#define SCAN_LDS_BYTES (SC_LDS_U + SC_LDS_H + SC_LDS_Z)

__global__ __launch_bounds__(256) void lstm_scan(
    const unsigned short* __restrict__ xz,   // [TCH][NB][2048] bf16 (x@W chunk)
    const unsigned short* __restrict__ UT,   // [2048][512] bf16
    const float* __restrict__ bias,          // [2048] f32
    unsigned short* __restrict__ x_out,      // [NS][NB][512] bf16 (full)
    unsigned short* __restrict__ h_buf,      // [2][8][16 ks][32 r][32] bf16
    float* __restrict__ c_buf,               // [NB][512] f32
    unsigned int* __restrict__ flags,        // [8][NS] (this layer)
    int t0, int t1)
{
  extern __shared__ char smem[];
  unsigned short* Uf = (unsigned short*)smem;
  char* Ha = smem + SC_LDS_U;
  float* Zl = (float*)(smem + SC_LDS_U + SC_LDS_H);
  const int tid = threadIdx.x, w = tid >> 6, l = tid & 63;
  const int group = blockIdx.x & 7;
  const int u0 = (blockIdx.x >> 3) * 16;

  // Load U fragments (frag-linear: idx = ks*256 + gate*64 + lane, 16B each)
  for (int idx = tid; idx < 4096; idx += 256) {
    int ll = idx & 63, nt = (idx >> 6) & 3, ks = idx >> 8;
    int gc = nt * NH + u0 + (ll & 15);
    int kb = ks * 32 + (ll >> 4) * 8;
    u32x4 v = *(const u32x4*)(UT + (size_t)gc * NH + kb);
    *(u32x4*)((char*)Uf + (size_t)idx * 16) = v;
  }
  // Zero h staging (h0 = 0; only meaningful when t0 == 0)
  for (int i = tid; i < SC_LDS_H / 16; i += 256)
    *(u32x4*)(Ha + (size_t)i * 16) = (u32x4)0u;

  const int j2 = tid & 15;
  const int r0 = tid >> 4;                 // rows r0 and r0+16 of the group
  const int n_ = u0 + j2;
  float biasv[4];
  #pragma unroll
  for (int G = 0; G < 4; ++G) biasv[G] = bias[G * NH + n_];
  float c_state[2];
  if (t0 == 0) { c_state[0] = 0.f; c_state[1] = 0.f; }
  else {
    c_state[0] = c_buf[(size_t)(group * 32 + r0) * NH + n_];
    c_state[1] = c_buf[(size_t)(group * 32 + r0 + 16) * NH + n_];
  }
  const int brow0 = group * 32 + r0;
  const int hwo = group * 16384 + (n_ >> 5) * 1024 + (n_ & 31); // + r*32, + par*131072
  unsigned int* flagp = flags + group * NS;

  __syncthreads();   // Uf + zeroed Ha visible

  for (int t = t0; t < t1; ++t) {
    const int tl = t - t0;
    if (t > 0) {
      if ((tid & 63) == 0) {               // lane 0 of each wave acquire-polls
        unsigned int spin = 0;
        while (__hip_atomic_load(flagp + (t - 1), __ATOMIC_ACQUIRE, __HIP_MEMORY_SCOPE_AGENT) < 32u) {
          __builtin_amdgcn_s_sleep(1);
          if (++spin > (1u << 16)) break;  // safety: degrade, don't hang
        }
      }
      __syncthreads();
      const unsigned short* hsrc = h_buf + (size_t)(t & 1) * 131072 + group * 16384;
      #pragma unroll
      for (int i = 0; i < 8; ++i) {
        int g = tid + i * 256;             // 16B chunk id, 2048 total
        u32x4 v = *(const u32x4*)(hsrc + (size_t)g * 8);
        int ks = g >> 7, rem = g & 127, rr = rem >> 2, cq = rem & 3;
        *(u32x4*)(Ha + ks * 2560 + rr * 80 + cq * 16) = v;
      }
    }
    // prefetch xz for this step (independent of h)
    unsigned short xzv[2][4];
    #pragma unroll
    for (int G = 0; G < 4; ++G) {
      xzv[0][G] = xz[((size_t)tl * NB + brow0) * N4H + G * NH + n_];
      xzv[1][G] = xz[((size_t)tl * NB + brow0 + 16) * N4H + G * NH + n_];
    }
    __syncthreads();  // staging visible

    f32x4 acc0 = (f32x4)0.f, acc1 = (f32x4)0.f;
    #pragma unroll
    for (int ks = 0; ks < 16; ++ks) {
      short8 bfr = *(const short8*)((char*)Uf + ((size_t)(ks * 4 + w) * 64 + l) * 16);
      short8 a0 = *(const short8*)(Ha + ks * 2560 + (l & 15) * 80 + (l >> 4) * 16);
      short8 a1 = *(const short8*)(Ha + ks * 2560 + ((l & 15) + 16) * 80 + (l >> 4) * 16);
      acc0 = __builtin_amdgcn_mfma_f32_16x16x32_bf16(a0, bfr, acc0, 0, 0, 0);
      acc1 = __builtin_amdgcn_mfma_f32_16x16x32_bf16(a1, bfr, acc1, 0, 0, 0);
    }
    #pragma unroll
    for (int i = 0; i < 4; ++i) {
      Zl[((l >> 4) * 4 + i) * 65 + w * 16 + (l & 15)] = acc0[i];
      Zl[((l >> 4) * 4 + i + 16) * 65 + w * 16 + (l & 15)] = acc1[i];
    }
    __syncthreads();  // z visible

    #pragma unroll
    for (int p = 0; p < 2; ++p) {
      int r = r0 + p * 16;
      float zi = Zl[r * 65 +      j2] + bf2f(xzv[p][0]) + biasv[0];
      float zf = Zl[r * 65 + 16 + j2] + bf2f(xzv[p][1]) + biasv[1];
      float zg = Zl[r * 65 + 32 + j2] + bf2f(xzv[p][2]) + biasv[2];
      float zo = Zl[r * 65 + 48 + j2] + bf2f(xzv[p][3]) + biasv[3];
      float ig = 1.f / (1.f + __expf(-zi));
      float fg = 1.f / (1.f + __expf(-zf));
      float gg = 1.f - 2.f / (__expf(2.f * zg) + 1.f);   // robust tanh
      float og = 1.f / (1.f + __expf(-zo));
      float c = fg * c_state[p] + ig * gg;
      c_state[p] = c;
      float th = 1.f - 2.f / (__expf(2.f * c) + 1.f);
      float h = og * th;
      unsigned short hb = f2bf(h);
      x_out[((size_t)t * NB + brow0 + p * 16) * NH + n_] = hb;
      h_buf[(size_t)((t + 1) & 1) * 131072 + hwo + r * 32] = hb;
    }
    __threadfence();
    __syncthreads();
    if (tid == 0)
      __hip_atomic_fetch_add(flagp + t, 1u, __ATOMIC_RELEASE, __HIP_MEMORY_SCOPE_AGENT);
  }
  // persist cell state for next chunk
  c_buf[(size_t)(group * 32 + r0) * NH + n_] = c_state[0];
  c_buf[(size_t)(group * 32 + r0 + 16) * NH + n_] = c_state[1];
}

// ---------------------------------------------------------------------------
extern "C" void kernel_launch(void* const* d_in, const int* in_sizes, int n_in,
                              void* d_out, int out_size, void* d_ws, size_t ws_size,
                              hipStream_t stream) {
  const int*   tokens = (const int*)  d_in[0];
  const float* emb    = (const float*)d_in[1];
  const float* w0     = (const float*)d_in[2];
  const float* u0     = (const float*)d_in[3];
  const float* b0     = (const float*)d_in[4];
  const float* w_rest = (const float*)d_in[5];
  const float* u_rest = (const float*)d_in[6];
  const float* b_rest = (const float*)d_in[7];
  const float* dw1    = (const float*)d_in[8];
  const float* db1    = (const float*)d_in[9];
  const float* dw2    = (const float*)d_in[10];
  const float* db2    = (const float*)d_in[11];
  float* out = (float*)d_out;

  char* ws = (char*)d_ws;
  size_t off = 0;
  auto alloc = [&](size_t bytes) -> char* {
    char* p = ws + off;
    off += (bytes + 255) & ~(size_t)255;
    return p;
  };
  unsigned short* ut[4];
  for (int i = 0; i < 4; ++i) ut[i] = (unsigned short*)alloc((size_t)N4H * NH * 2);
  unsigned short* w0t = (unsigned short*)alloc((size_t)N4H * NE * 2);
  unsigned short* wt[3];
  for (int i = 0; i < 3; ++i) wt[i] = (unsigned short*)alloc((size_t)N4H * NH * 2);
  unsigned short* dw1t = (unsigned short*)alloc((size_t)1024 * 512 * 2);
  unsigned short* dw2t = (unsigned short*)alloc((size_t)32 * 1024 * 2);
  unsigned short* x0  = (unsigned short*)alloc((size_t)NB * NS * NE * 2);
  unsigned short* xA  = (unsigned short*)alloc((size_t)NB * NS * NH * 2);
  unsigned short* hb  = (unsigned short*)alloc((size_t)2 * 8 * 16384 * 2);
  float*          cb  = (float*)alloc((size_t)NB * NH * 4);
  unsigned int* flags = (unsigned int*)alloc((size_t)4 * 8 * NS * 4);
  size_t fixed = off;

  // ws-adaptive time-chunk: xz chunk is [TCH][NB][4H] bf16 = TCH MB
  int TCH = NS;
  while (TCH > 32 && fixed + (size_t)NB * TCH * N4H * 2 > ws_size) TCH >>= 1;
  unsigned short* xzc = (unsigned short*)alloc((size_t)NB * TCH * N4H * 2);

  (void)hipMemsetAsync(flags, 0, (size_t)4 * 8 * NS * 4, stream);

  // Weight transposes (f32 [K][N] -> bf16 [N][K])
  transpose_cast<<<dim3(1, N4H), 256, 0, stream>>>(w0, w0t, NE, N4H);
  transpose_cast<<<dim3(2, N4H), 256, 0, stream>>>(u0, ut[0], NH, N4H);
  for (int i = 0; i < 3; ++i) {
    transpose_cast<<<dim3(2, N4H), 256, 0, stream>>>(w_rest + (size_t)i * NH * N4H, wt[i], NH, N4H);
    transpose_cast<<<dim3(2, N4H), 256, 0, stream>>>(u_rest + (size_t)i * NH * N4H, ut[i + 1], NH, N4H);
  }
  transpose_cast<<<dim3(2, 1024), 256, 0, stream>>>(dw1, dw1t, 512, 1024);
  transpose_cast<<<dim3(4, 32), 256, 0, stream>>>(dw2, dw2t, 1024, 32);

  embed_kernel<<<16384, 256, 0, stream>>>(tokens, emb, x0);

  (void)hipFuncSetAttribute((const void*)lstm_scan,
                            hipFuncAttributeMaxDynamicSharedMemorySize, SCAN_LDS_BYTES);

  const unsigned short* xin = x0;
  int kdim = NE;
  for (int lyr = 0; lyr < 4; ++lyr) {
    const unsigned short* wTl = (lyr == 0) ? w0t : wt[lyr - 1];
    const float* bl = (lyr == 0) ? b0 : (b_rest + (size_t)(lyr - 1) * N4H);
    for (int t0 = 0; t0 < NS; t0 += TCH) {
      gemm_bt<128, 128, false, false, false, false>
          <<<dim3(N4H / 128, TCH * NB / 128), 256, 0, stream>>>(
              xin + (size_t)t0 * NB * kdim, wTl, xzc, nullptr, TCH * NB, N4H, kdim, 0);
      lstm_scan<<<256, 256, SCAN_LDS_BYTES, stream>>>(
          xzc, ut[lyr], bl, xA, hb, cb, flags + (size_t)lyr * 8 * NS, t0, t0 + TCH);
    }
    xin = xA;       // scan overwrote its input layer's x in place (safe: GEMM consumed it)
    kdim = NH;
  }

  // Dense head, row-chunked through xzc: h1 = relu(x@dw1+db1); out = h1@dw2+db2
  size_t chunkbytes = (size_t)NB * TCH * N4H * 2;
  long RC = (long)(chunkbytes / ((size_t)1024 * 2));
  if (RC > (long)NB * NS) RC = (long)NB * NS;
  RC &= ~(long)127;
  for (long r0 = 0; r0 < (long)NB * NS; r0 += RC) {
    long rows = ((long)NB * NS - r0 < RC) ? ((long)NB * NS - r0) : RC;
    gemm_bt<128, 128, true, true, false, false>
        <<<dim3(1024 / 128, rows / 128), 256, 0, stream>>>(
            xA + (size_t)r0 * NH, dw1t, xzc, db1, (int)rows, 1024, NH, 0);
    gemm_bt<128, 32, true, false, true, true>
        <<<dim3(1, rows / 128), 256, 0, stream>>>(
            xzc, dw2t, out, db2, (int)rows, 32, 1024, (int)r0);
  }
}

// Round 4
// 25412.238 us; speedup vs baseline: 3.2725x; 3.2725x over previous
//
#include <hip/hip_runtime.h>
#include <stdint.h>

// Problem constants
#define NB 256      // batch
#define NS 512      // seq
#define NV 32       // vocab
#define NE 128      // embed
#define NH 512      // rnn units
#define N4H 2048    // 4*H

typedef __attribute__((ext_vector_type(8))) short short8;
typedef __attribute__((ext_vector_type(4))) float f32x4;
typedef __attribute__((ext_vector_type(4))) unsigned int u32x4;
typedef __attribute__((ext_vector_type(4))) unsigned short u16x4;

__device__ __forceinline__ float bf2f(unsigned short u){
  unsigned int x = ((unsigned int)u) << 16;
  return __builtin_bit_cast(float, x);
}
__device__ __forceinline__ unsigned short f2bf(float f){
  unsigned int u = __builtin_bit_cast(unsigned int, f);
  u += 0x7fffu + ((u >> 16) & 1u);
  return (unsigned short)(u >> 16);
}
// async global->LDS, 16B per lane; LDS dest = wave-uniform base + lane*16
__device__ __forceinline__ void gload_lds16(const void* g, void* l){
  __builtin_amdgcn_global_load_lds(
      (const __attribute__((address_space(1))) unsigned int*)(uintptr_t)g,
      (__attribute__((address_space(3))) unsigned int*)(uintptr_t)l,
      16, 0, 0);
}

// ---------------------------------------------------------------------------
// Transpose + cast f32 [K][N] -> bf16 [N][K]
// ---------------------------------------------------------------------------
__global__ __launch_bounds__(256) void transpose_cast(
    const float* __restrict__ in, unsigned short* __restrict__ out, int K, int N)
{
  int k = blockIdx.x * 256 + threadIdx.x;
  int n = blockIdx.y;
  if (k < K) out[(long)n * K + k] = f2bf(in[(long)k * N + n]);
}

// ---------------------------------------------------------------------------
// Embedding (time-major): x0[t][b][e] = bf16(emb[tok[b][t]][e] * sqrt(128))
// ---------------------------------------------------------------------------
__global__ __launch_bounds__(256) void embed_kernel(
    const int* __restrict__ tok, const float* __restrict__ emb,
    unsigned short* __restrict__ x0)
{
  long gid = (long)blockIdx.x * 256 + threadIdx.x;
  long idx = gid * 4;                     // element index into [NS][NB][NE]
  int e = (int)(idx & 127);
  int b = (int)((idx >> 7) & 255);
  int t = (int)(idx >> 15);
  int tk = tok[b * NS + t];
  f32x4 v = *(const f32x4*)(emb + (long)tk * NE + e);
  u16x4 o;
  #pragma unroll
  for (int i = 0; i < 4; ++i) o[i] = f2bf(v[i] * 11.313708498984761f);
  *(u16x4*)(x0 + idx) = o;
}

// ---------------------------------------------------------------------------
// GEMM: C[M][N] = A[M][K] * BT[N][K]^T  (+bias, +relu, f32/bf16 out, row remap)
// m97-style: 256 thr, BK=64, global_load_lds staging, 16x16x32 bf16 MFMA
// ---------------------------------------------------------------------------
template<int BM, int BN, bool BIAS, bool RELU, bool F32OUT, bool REMAP>
__global__ __launch_bounds__(256) void gemm_bt(
    const unsigned short* __restrict__ A, const unsigned short* __restrict__ BT,
    void* __restrict__ Cv, const float* __restrict__ bias,
    int M, int N, int K, int rowoff)
{
  constexpr int BK = 64;
  constexpr int WN = (BN >= 64) ? 2 : 1;
  constexpr int WM = 4 / WN;
  constexpr int WTM = BM / WM, WTN = BN / WN;
  constexpr int FM = WTM / 16, FN = WTN / 16;
  __shared__ unsigned short lds[(BM + BN) * BK];
  unsigned short* As = lds;
  unsigned short* Bs = lds + BM * BK;
  const int tid = threadIdx.x;
  const int w = tid >> 6, l = tid & 63;
  const int n0 = blockIdx.x * BN, m0 = blockIdx.y * BM;
  const int wm = (WN == 2) ? (w >> 1) : w;
  const int wn = (WN == 2) ? (w & 1) : 0;

  f32x4 acc[FM][FN];
  #pragma unroll
  for (int i = 0; i < FM; i++)
    #pragma unroll
    for (int j = 0; j < FN; j++) acc[i][j] = (f32x4)0.f;

  constexpr int CH_A = BM * 8;            // 16B chunks in A region
  constexpr int CH_T = (BM + BN) * 8;
  constexpr int PW = CH_T / 4;
  static_assert(PW % 64 == 0, "staging alignment");
  static_assert(CH_A % 64 == 0, "region boundary alignment");

  for (int kt = 0; kt < K; kt += BK) {
    #pragma unroll
    for (int i = 0; i < PW / 64; ++i) {
      int c0 = w * PW + i * 64;           // wave-uniform
      int c = c0 + l;
      const unsigned short* g;
      if (c0 < CH_A) {
        int row = c >> 3, col = c & 7;
        g = A + (long)(m0 + row) * K + kt + col * 8;
      } else {
        int cb = c - CH_A;
        int row = cb >> 3, col = cb & 7;
        g = BT + (long)(n0 + row) * K + kt + col * 8;
      }
      gload_lds16(g, lds + (size_t)c0 * 8);
    }
    __syncthreads();
    #pragma unroll
    for (int ks = 0; ks < BK / 32; ++ks) {
      short8 a[FM], b[FN];
      #pragma unroll
      for (int mt = 0; mt < FM; ++mt)
        a[mt] = *(const short8*)&As[(wm * WTM + mt * 16 + (l & 15)) * BK + ks * 32 + (l >> 4) * 8];
      #pragma unroll
      for (int nt = 0; nt < FN; ++nt)
        b[nt] = *(const short8*)&Bs[(wn * WTN + nt * 16 + (l & 15)) * BK + ks * 32 + (l >> 4) * 8];
      #pragma unroll
      for (int mt = 0; mt < FM; ++mt)
        #pragma unroll
        for (int nt = 0; nt < FN; ++nt)
          acc[mt][nt] = __builtin_amdgcn_mfma_f32_16x16x32_bf16(a[mt], b[nt], acc[mt][nt], 0, 0, 0);
    }
    __syncthreads();
  }

  const int row_l = l >> 4, col_l = l & 15;
  #pragma unroll
  for (int nt = 0; nt < FN; ++nt) {
    int col = n0 + wn * WTN + nt * 16 + col_l;
    float bv = 0.f;
    if (BIAS) bv = bias[col];
    #pragma unroll
    for (int mt = 0; mt < FM; ++mt) {
      #pragma unroll
      for (int i = 0; i < 4; ++i) {
        int m = m0 + wm * WTM + mt * 16 + row_l * 4 + i;
        float v = acc[mt][nt][i] + bv;
        if (RELU) v = v > 0.f ? v : 0.f;
        long cidx;
        if (REMAP) {
          int gr = rowoff + m;            // global time-major row = t*NB + b
          int b_ = gr & (NB - 1), t_ = gr >> 8;
          cidx = ((long)b_ * NS + t_) * N + col;
        } else {
          cidx = (long)m * N + col;
        }
        if (F32OUT) ((float*)Cv)[cidx] = v;
        else ((unsigned short*)Cv)[cidx] = f2bf(v);
      }
    }
  }
}

// ---------------------------------------------------------------------------
// LSTM scan chunk: persistent 256-WG kernel (1 block/CU via LDS).
// 8 batch-groups x 32 unit-slice WGs. WG owns 16 hidden units (64 gate cols)
// for 32 batch rows; U-slice resident in LDS.
// Sync protocol (round-4 fix): RELAXED agent polls (no per-poll buffer_inv!),
// ONE acquire fence per WG per step after flag observed; release = barrier
// (drains vmcnt) + tid0 {release fence (one wbl2) + relaxed flag add}.
// Round-3 acquire-loads-in-loop caused whole-L2 invalidates per poll
// -> 70 GB FETCH, 30-43 ms/dispatch.
// ---------------------------------------------------------------------------
#define SC_LDS_U 65536            // 16ks x 4gate x 64lane x 16B (frag-linear)
#define SC_LDS_H (16 * 32 * 80)   // [16 ks][32 r][80B: 64B data + 16B pad]
#define SC_LDS_Z (32 * 65 * 4)    // z exchange [32][65] f32
#define SCAN_LDS_BYTES (SC_LDS_U + SC_LDS_H + SC_LDS_Z)

__global__ __launch_bounds__(256) void lstm_scan(
    const unsigned short* __restrict__ xz,   // [TCH][NB][2048] bf16 (x@W chunk)
    const unsigned short* __restrict__ UT,   // [2048][512] bf16
    const float* __restrict__ bias,          // [2048] f32
    unsigned short* __restrict__ x_out,      // [NS][NB][512] bf16 (full)
    unsigned short* __restrict__ h_buf,      // [2][8][16 ks][32 r][32] bf16
    float* __restrict__ c_buf,               // [NB][512] f32
    unsigned int* __restrict__ flags,        // [8][NS] (this layer)
    int t0, int t1)
{
  extern __shared__ char smem[];
  unsigned short* Uf = (unsigned short*)smem;
  char* Ha = smem + SC_LDS_U;
  float* Zl = (float*)(smem + SC_LDS_U + SC_LDS_H);
  const int tid = threadIdx.x, w = tid >> 6, l = tid & 63;
  const int group = blockIdx.x & 7;
  const int u0 = (blockIdx.x >> 3) * 16;

  // Load U fragments (frag-linear: idx = ks*256 + gate*64 + lane, 16B each)
  for (int idx = tid; idx < 4096; idx += 256) {
    int ll = idx & 63, nt = (idx >> 6) & 3, ks = idx >> 8;
    int gc = nt * NH + u0 + (ll & 15);
    int kb = ks * 32 + (ll >> 4) * 8;
    u32x4 v = *(const u32x4*)(UT + (size_t)gc * NH + kb);
    *(u32x4*)((char*)Uf + (size_t)idx * 16) = v;
  }
  // Zero h staging (h0 = 0; only meaningful when t0 == 0)
  for (int i = tid; i < SC_LDS_H / 16; i += 256)
    *(u32x4*)(Ha + (size_t)i * 16) = (u32x4)0u;

  const int j2 = tid & 15;
  const int r0 = tid >> 4;                 // rows r0 and r0+16 of the group
  const int n_ = u0 + j2;
  float biasv[4];
  #pragma unroll
  for (int G = 0; G < 4; ++G) biasv[G] = bias[G * NH + n_];
  float c_state[2];
  if (t0 == 0) { c_state[0] = 0.f; c_state[1] = 0.f; }
  else {
    c_state[0] = c_buf[(size_t)(group * 32 + r0) * NH + n_];
    c_state[1] = c_buf[(size_t)(group * 32 + r0 + 16) * NH + n_];
  }
  const int brow0 = group * 32 + r0;
  const int hwo = group * 16384 + (n_ >> 5) * 1024 + (n_ & 31); // + r*32, + par*131072
  unsigned int* flagp = flags + group * NS;

  __syncthreads();   // Uf + zeroed Ha visible

  for (int t = t0; t < t1; ++t) {
    const int tl = t - t0;
    // prefetch xz for this step (independent of h) — overlaps the flag wait
    unsigned short xzv[2][4];
    #pragma unroll
    for (int G = 0; G < 4; ++G) {
      xzv[0][G] = xz[((size_t)tl * NB + brow0) * N4H + G * NH + n_];
      xzv[1][G] = xz[((size_t)tl * NB + brow0 + 16) * N4H + G * NH + n_];
    }
    if (t > 0) {
      if (tid == 0) {
        unsigned int spin = 0;
        while (__hip_atomic_load(flagp + (t - 1), __ATOMIC_RELAXED, __HIP_MEMORY_SCOPE_AGENT) < 32u) {
          __builtin_amdgcn_s_sleep(2);
          if (++spin > (1u << 18)) break;  // safety: degrade, don't hang
        }
        // one L1+L2 invalidate per WG per step (WG = one CU; shared L1)
        __builtin_amdgcn_fence(__ATOMIC_ACQUIRE, "agent");
      }
      __syncthreads();                     // rest of WG waits behind the fence
      const unsigned short* hsrc = h_buf + (size_t)(t & 1) * 131072 + group * 16384;
      #pragma unroll
      for (int i = 0; i < 8; ++i) {
        int g = tid + i * 256;             // 16B chunk id, 2048 total
        u32x4 v = *(const u32x4*)(hsrc + (size_t)g * 8);
        int ks = g >> 7, rem = g & 127, rr = rem >> 2, cq = rem & 3;
        *(u32x4*)(Ha + ks * 2560 + rr * 80 + cq * 16) = v;
      }
    }
    __syncthreads();  // staging visible

    f32x4 acc0 = (f32x4)0.f, acc1 = (f32x4)0.f;
    #pragma unroll
    for (int ks = 0; ks < 16; ++ks) {
      short8 bfr = *(const short8*)((char*)Uf + ((size_t)(ks * 4 + w) * 64 + l) * 16);
      short8 a0 = *(const short8*)(Ha + ks * 2560 + (l & 15) * 80 + (l >> 4) * 16);
      short8 a1 = *(const short8*)(Ha + ks * 2560 + ((l & 15) + 16) * 80 + (l >> 4) * 16);
      acc0 = __builtin_amdgcn_mfma_f32_16x16x32_bf16(a0, bfr, acc0, 0, 0, 0);
      acc1 = __builtin_amdgcn_mfma_f32_16x16x32_bf16(a1, bfr, acc1, 0, 0, 0);
    }
    #pragma unroll
    for (int i = 0; i < 4; ++i) {
      Zl[((l >> 4) * 4 + i) * 65 + w * 16 + (l & 15)] = acc0[i];
      Zl[((l >> 4) * 4 + i + 16) * 65 + w * 16 + (l & 15)] = acc1[i];
    }
    __syncthreads();  // z visible

    #pragma unroll
    for (int p = 0; p < 2; ++p) {
      int r = r0 + p * 16;
      float zi = Zl[r * 65 +      j2] + bf2f(xzv[p][0]) + biasv[0];
      float zf = Zl[r * 65 + 16 + j2] + bf2f(xzv[p][1]) + biasv[1];
      float zg = Zl[r * 65 + 32 + j2] + bf2f(xzv[p][2]) + biasv[2];
      float zo = Zl[r * 65 + 48 + j2] + bf2f(xzv[p][3]) + biasv[3];
      float ig = 1.f / (1.f + __expf(-zi));
      float fg = 1.f / (1.f + __expf(-zf));
      float gg = 1.f - 2.f / (__expf(2.f * zg) + 1.f);   // robust tanh
      float og = 1.f / (1.f + __expf(-zo));
      float c = fg * c_state[p] + ig * gg;
      c_state[p] = c;
      float th = 1.f - 2.f / (__expf(2.f * c) + 1.f);
      float h = og * th;
      unsigned short hb = f2bf(h);
      x_out[((size_t)t * NB + brow0 + p * 16) * NH + n_] = hb;
      h_buf[(size_t)((t + 1) & 1) * 131072 + hwo + r * 32] = hb;
    }
    // release: barrier drains vmcnt (stores in L2), then one wbl2 + flag add
    __syncthreads();
    if (tid == 0) {
      __builtin_amdgcn_fence(__ATOMIC_RELEASE, "agent");
      __hip_atomic_fetch_add(flagp + t, 1u, __ATOMIC_RELAXED, __HIP_MEMORY_SCOPE_AGENT);
    }
  }
  // persist cell state for next chunk
  c_buf[(size_t)(group * 32 + r0) * NH + n_] = c_state[0];
  c_buf[(size_t)(group * 32 + r0 + 16) * NH + n_] = c_state[1];
}

// ---------------------------------------------------------------------------
extern "C" void kernel_launch(void* const* d_in, const int* in_sizes, int n_in,
                              void* d_out, int out_size, void* d_ws, size_t ws_size,
                              hipStream_t stream) {
  const int*   tokens = (const int*)  d_in[0];
  const float* emb    = (const float*)d_in[1];
  const float* w0     = (const float*)d_in[2];
  const float* u0     = (const float*)d_in[3];
  const float* b0     = (const float*)d_in[4];
  const float* w_rest = (const float*)d_in[5];
  const float* u_rest = (const float*)d_in[6];
  const float* b_rest = (const float*)d_in[7];
  const float* dw1    = (const float*)d_in[8];
  const float* db1    = (const float*)d_in[9];
  const float* dw2    = (const float*)d_in[10];
  const float* db2    = (const float*)d_in[11];
  float* out = (float*)d_out;

  char* ws = (char*)d_ws;
  size_t off = 0;
  auto alloc = [&](size_t bytes) -> char* {
    char* p = ws + off;
    off += (bytes + 255) & ~(size_t)255;
    return p;
  };
  unsigned short* ut[4];
  for (int i = 0; i < 4; ++i) ut[i] = (unsigned short*)alloc((size_t)N4H * NH * 2);
  unsigned short* w0t = (unsigned short*)alloc((size_t)N4H * NE * 2);
  unsigned short* wt[3];
  for (int i = 0; i < 3; ++i) wt[i] = (unsigned short*)alloc((size_t)N4H * NH * 2);
  unsigned short* dw1t = (unsigned short*)alloc((size_t)1024 * 512 * 2);
  unsigned short* dw2t = (unsigned short*)alloc((size_t)32 * 1024 * 2);
  unsigned short* x0  = (unsigned short*)alloc((size_t)NB * NS * NE * 2);
  unsigned short* xA  = (unsigned short*)alloc((size_t)NB * NS * NH * 2);
  unsigned short* hb  = (unsigned short*)alloc((size_t)2 * 8 * 16384 * 2);
  float*          cb  = (float*)alloc((size_t)NB * NH * 4);
  unsigned int* flags = (unsigned int*)alloc((size_t)4 * 8 * NS * 4);
  size_t fixed = off;

  // ws-adaptive time-chunk: xz chunk is [TCH][NB][4H] bf16 = TCH MB
  int TCH = NS;
  while (TCH > 32 && fixed + (size_t)NB * TCH * N4H * 2 > ws_size) TCH >>= 1;
  unsigned short* xzc = (unsigned short*)alloc((size_t)NB * TCH * N4H * 2);

  (void)hipMemsetAsync(flags, 0, (size_t)4 * 8 * NS * 4, stream);

  // Weight transposes (f32 [K][N] -> bf16 [N][K])
  transpose_cast<<<dim3(1, N4H), 256, 0, stream>>>(w0, w0t, NE, N4H);
  transpose_cast<<<dim3(2, N4H), 256, 0, stream>>>(u0, ut[0], NH, N4H);
  for (int i = 0; i < 3; ++i) {
    transpose_cast<<<dim3(2, N4H), 256, 0, stream>>>(w_rest + (size_t)i * NH * N4H, wt[i], NH, N4H);
    transpose_cast<<<dim3(2, N4H), 256, 0, stream>>>(u_rest + (size_t)i * NH * N4H, ut[i + 1], NH, N4H);
  }
  transpose_cast<<<dim3(2, 1024), 256, 0, stream>>>(dw1, dw1t, 512, 1024);
  transpose_cast<<<dim3(4, 32), 256, 0, stream>>>(dw2, dw2t, 1024, 32);

  embed_kernel<<<16384, 256, 0, stream>>>(tokens, emb, x0);

  (void)hipFuncSetAttribute((const void*)lstm_scan,
                            hipFuncAttributeMaxDynamicSharedMemorySize, SCAN_LDS_BYTES);

  const unsigned short* xin = x0;
  int kdim = NE;
  for (int lyr = 0; lyr < 4; ++lyr) {
    const unsigned short* wTl = (lyr == 0) ? w0t : wt[lyr - 1];
    const float* bl = (lyr == 0) ? b0 : (b_rest + (size_t)(lyr - 1) * N4H);
    for (int t0 = 0; t0 < NS; t0 += TCH) {
      gemm_bt<128, 128, false, false, false, false>
          <<<dim3(N4H / 128, TCH * NB / 128), 256, 0, stream>>>(
              xin + (size_t)t0 * NB * kdim, wTl, xzc, nullptr, TCH * NB, N4H, kdim, 0);
      lstm_scan<<<256, 256, SCAN_LDS_BYTES, stream>>>(
          xzc, ut[lyr], bl, xA, hb, cb, flags + (size_t)lyr * 8 * NS, t0, t0 + TCH);
    }
    xin = xA;       // scan overwrote its input layer's x in place (safe: GEMM consumed it)
    kdim = NH;
  }

  // Dense head, row-chunked through xzc: h1 = relu(x@dw1+db1); out = h1@dw2+db2
  size_t chunkbytes = (size_t)NB * TCH * N4H * 2;
  long RC = (long)(chunkbytes / ((size_t)1024 * 2));
  if (RC > (long)NB * NS) RC = (long)NB * NS;
  RC &= ~(long)127;
  for (long r0 = 0; r0 < (long)NB * NS; r0 += RC) {
    long rows = ((long)NB * NS - r0 < RC) ? ((long)NB * NS - r0) : RC;
    gemm_bt<128, 128, true, true, false, false>
        <<<dim3(1024 / 128, rows / 128), 256, 0, stream>>>(
            xA + (size_t)r0 * NH, dw1t, xzc, db1, (int)rows, 1024, NH, 0);
    gemm_bt<128, 32, true, false, true, true>
        <<<dim3(1, rows / 128), 256, 0, stream>>>(
            xzc, dw2t, out, db2, (int)rows, 32, 1024, (int)r0);
  }
}

// Round 5
// 11555.759 us; speedup vs baseline: 7.1965x; 2.1991x over previous
//
#include <hip/hip_runtime.h>
#include <stdint.h>

// Problem constants
#define NB 256      // batch
#define NS 512      // seq
#define NV 32       // vocab
#define NE 128      // embed
#define NH 512      // rnn units
#define N4H 2048    // 4*H

typedef __attribute__((ext_vector_type(8))) short short8;
typedef __attribute__((ext_vector_type(4))) float f32x4;
typedef __attribute__((ext_vector_type(4))) unsigned int u32x4;
typedef __attribute__((ext_vector_type(4))) unsigned short u16x4;

__device__ __forceinline__ float bf2f(unsigned short u){
  unsigned int x = ((unsigned int)u) << 16;
  return __builtin_bit_cast(float, x);
}
__device__ __forceinline__ unsigned short f2bf(float f){
  unsigned int u = __builtin_bit_cast(unsigned int, f);
  u += 0x7fffu + ((u >> 16) & 1u);
  return (unsigned short)(u >> 16);
}
// async global->LDS, 16B per lane; LDS dest = wave-uniform base + lane*16
__device__ __forceinline__ void gload_lds16(const void* g, void* l){
  __builtin_amdgcn_global_load_lds(
      (const __attribute__((address_space(1))) unsigned int*)(uintptr_t)g,
      (__attribute__((address_space(3))) unsigned int*)(uintptr_t)l,
      16, 0, 0);
}

// ---------------------------------------------------------------------------
// Transpose + cast f32 [K][N] -> bf16 [N][K]
// ---------------------------------------------------------------------------
__global__ __launch_bounds__(256) void transpose_cast(
    const float* __restrict__ in, unsigned short* __restrict__ out, int K, int N)
{
  int k = blockIdx.x * 256 + threadIdx.x;
  int n = blockIdx.y;
  if (k < K) out[(long)n * K + k] = f2bf(in[(long)k * N + n]);
}

// ---------------------------------------------------------------------------
// Embedding (time-major): x0[t][b][e] = bf16(emb[tok[b][t]][e] * sqrt(128))
// ---------------------------------------------------------------------------
__global__ __launch_bounds__(256) void embed_kernel(
    const int* __restrict__ tok, const float* __restrict__ emb,
    unsigned short* __restrict__ x0)
{
  long gid = (long)blockIdx.x * 256 + threadIdx.x;
  long idx = gid * 4;                     // element index into [NS][NB][NE]
  int e = (int)(idx & 127);
  int b = (int)((idx >> 7) & 255);
  int t = (int)(idx >> 15);
  int tk = tok[b * NS + t];
  f32x4 v = *(const f32x4*)(emb + (long)tk * NE + e);
  u16x4 o;
  #pragma unroll
  for (int i = 0; i < 4; ++i) o[i] = f2bf(v[i] * 11.313708498984761f);
  *(u16x4*)(x0 + idx) = o;
}

// ---------------------------------------------------------------------------
// GEMM: C[M][N] = A[M][K] * BT[N][K]^T  (+bias, +relu, f32/bf16 out, row remap)
// m97-style: 256 thr, BK=64, global_load_lds staging, 16x16x32 bf16 MFMA
// (used for the dense head only)
// ---------------------------------------------------------------------------
template<int BM, int BN, bool BIAS, bool RELU, bool F32OUT, bool REMAP>
__global__ __launch_bounds__(256) void gemm_bt(
    const unsigned short* __restrict__ A, const unsigned short* __restrict__ BT,
    void* __restrict__ Cv, const float* __restrict__ bias,
    int M, int N, int K, int rowoff)
{
  constexpr int BK = 64;
  constexpr int WN = (BN >= 64) ? 2 : 1;
  constexpr int WM = 4 / WN;
  constexpr int WTM = BM / WM, WTN = BN / WN;
  constexpr int FM = WTM / 16, FN = WTN / 16;
  __shared__ unsigned short lds[(BM + BN) * BK];
  unsigned short* As = lds;
  unsigned short* Bs = lds + BM * BK;
  const int tid = threadIdx.x;
  const int w = tid >> 6, l = tid & 63;
  const int n0 = blockIdx.x * BN, m0 = blockIdx.y * BM;
  const int wm = (WN == 2) ? (w >> 1) : w;
  const int wn = (WN == 2) ? (w & 1) : 0;

  f32x4 acc[FM][FN];
  #pragma unroll
  for (int i = 0; i < FM; i++)
    #pragma unroll
    for (int j = 0; j < FN; j++) acc[i][j] = (f32x4)0.f;

  constexpr int CH_A = BM * 8;            // 16B chunks in A region
  constexpr int CH_T = (BM + BN) * 8;
  constexpr int PW = CH_T / 4;
  static_assert(PW % 64 == 0, "staging alignment");
  static_assert(CH_A % 64 == 0, "region boundary alignment");

  for (int kt = 0; kt < K; kt += BK) {
    #pragma unroll
    for (int i = 0; i < PW / 64; ++i) {
      int c0 = w * PW + i * 64;           // wave-uniform
      int c = c0 + l;
      const unsigned short* g;
      if (c0 < CH_A) {
        int row = c >> 3, col = c & 7;
        g = A + (long)(m0 + row) * K + kt + col * 8;
      } else {
        int cb = c - CH_A;
        int row = cb >> 3, col = cb & 7;
        g = BT + (long)(n0 + row) * K + kt + col * 8;
      }
      gload_lds16(g, lds + (size_t)c0 * 8);
    }
    __syncthreads();
    #pragma unroll
    for (int ks = 0; ks < BK / 32; ++ks) {
      short8 a[FM], b[FN];
      #pragma unroll
      for (int mt = 0; mt < FM; ++mt)
        a[mt] = *(const short8*)&As[(wm * WTM + mt * 16 + (l & 15)) * BK + ks * 32 + (l >> 4) * 8];
      #pragma unroll
      for (int nt = 0; nt < FN; ++nt)
        b[nt] = *(const short8*)&Bs[(wn * WTN + nt * 16 + (l & 15)) * BK + ks * 32 + (l >> 4) * 8];
      #pragma unroll
      for (int mt = 0; mt < FM; ++mt)
        #pragma unroll
        for (int nt = 0; nt < FN; ++nt)
          acc[mt][nt] = __builtin_amdgcn_mfma_f32_16x16x32_bf16(a[mt], b[nt], acc[mt][nt], 0, 0, 0);
    }
    __syncthreads();
  }

  const int row_l = l >> 4, col_l = l & 15;
  #pragma unroll
  for (int nt = 0; nt < FN; ++nt) {
    int col = n0 + wn * WTN + nt * 16 + col_l;
    float bv = 0.f;
    if (BIAS) bv = bias[col];
    #pragma unroll
    for (int mt = 0; mt < FM; ++mt) {
      #pragma unroll
      for (int i = 0; i < 4; ++i) {
        int m = m0 + wm * WTM + mt * 16 + row_l * 4 + i;
        float v = acc[mt][nt][i] + bv;
        if (RELU) v = v > 0.f ? v : 0.f;
        long cidx;
        if (REMAP) {
          int gr = rowoff + m;            // global time-major row = t*NB + b
          int b_ = gr & (NB - 1), t_ = gr >> 8;
          cidx = ((long)b_ * NS + t_) * N + col;
        } else {
          cidx = (long)m * N + col;
        }
        if (F32OUT) ((float*)Cv)[cidx] = v;
        else ((unsigned short*)Cv)[cidx] = f2bf(v);
      }
    }
  }
}

// ---------------------------------------------------------------------------
// Fused LSTM scan: 256 WGs (1/CU via LDS), 8 batch-groups x 32 unit-slices.
// Per step per WG: zx = x_t @ W-slice (MFMA, A/B from L2-cached global,
// issued BEFORE the poll so it hides in the wait) + zh = h_{t-1} @ U-slice
// (U in LDS, h gathered from MALL). Cross-WG h exchange uses sc0 sc1
// loads/stores (L1+L2 bypass, served at Infinity Cache) — NO cache-wide
// fences (round-4's buffer_inv/wbl2 per step cost ~10 us/step).
// seq[group][slice] single-writer word; poll target (all seq >= t) implies
// both h_{t-1} ready and h_{t-2} readers done => 2-parity h_buf is safe.
// ---------------------------------------------------------------------------
#define SC_LDS_U 65536            // 16ks x 4gate x 64lane x 16B (frag-linear)
#define SC_LDS_H (16 * 32 * 80)   // [16 ks][32 r][80B: 64B data + 16B pad]
#define SC_LDS_Z (32 * 65 * 4)    // z exchange [32][65] f32
#define SCAN_LDS_BYTES (SC_LDS_U + SC_LDS_H + SC_LDS_Z)

template<int KD>
__global__ __launch_bounds__(256) void lstm_scan_fused(
    const unsigned short* __restrict__ x_in,  // [NS][NB][KD] bf16 (prev layer / x0)
    const unsigned short* __restrict__ WT,    // [2048][KD] bf16
    const unsigned short* __restrict__ UT,    // [2048][512] bf16
    const float* __restrict__ bias,           // [2048] f32
    unsigned short* __restrict__ x_out,       // [NS][NB][512] bf16
    unsigned short* __restrict__ h_buf,       // [2][8][16 ks][32 r][32] bf16
    unsigned int* __restrict__ seq)           // [8][32]
{
  constexpr int KS = KD / 32;
  extern __shared__ char smem[];
  unsigned short* Uf = (unsigned short*)smem;
  char* Ha = smem + SC_LDS_U;
  float* Zl = (float*)(smem + SC_LDS_U + SC_LDS_H);
  const int tid = threadIdx.x, w = tid >> 6, l = tid & 63;
  const int group = blockIdx.x & 7;
  const int slice = blockIdx.x >> 3;
  const int u0 = slice * 16;

  // U fragments into LDS (frag-linear: idx = ks*256 + gate*64 + lane, 16B)
  for (int idx = tid; idx < 4096; idx += 256) {
    int ll = idx & 63, nt = (idx >> 6) & 3, ks = idx >> 8;
    int gc = nt * NH + u0 + (ll & 15);
    int kb = ks * 32 + (ll >> 4) * 8;
    u32x4 v = *(const u32x4*)(UT + (size_t)gc * NH + kb);
    *(u32x4*)((char*)Uf + (size_t)idx * 16) = v;
  }

  const int j2 = tid & 15;
  const int r0 = tid >> 4;                 // rows r0 and r0+16 of the group
  const int n_ = u0 + j2;
  const int brow0 = group * 32 + r0;
  const float bv = bias[w * NH + u0 + (l & 15)];  // acc col = u0+(l&15), gate w
  float c_state[2] = {0.f, 0.f};
  const int hwo = group * 16384 + (n_ >> 5) * 1024 + (n_ & 31); // + r*32, + par*131072
  unsigned int* seqg = seq + group * 32;
  unsigned int* myseq = seqg + slice;
  const int ownlane = ((l & 31) == slice);
  // A-frag base for x (rows l&15 and +16 of the group), B-frag base for W
  const unsigned short* xr0 = x_in + (size_t)(group * 32 + (l & 15)) * KD + (l >> 4) * 8;
  const unsigned short* wp  = WT + (size_t)(w * NH + u0 + (l & 15)) * KD + (l >> 4) * 8;

  __syncthreads();   // Uf visible

  for (int t = 0; t < NS; ++t) {
    // ---- zx = x_t @ W-slice, acc init = bias (no h dependency; hides in wait)
    f32x4 acc0 = {bv, bv, bv, bv}, acc1 = {bv, bv, bv, bv};
    {
      const unsigned short* xa = xr0 + (size_t)t * NB * KD;
      #pragma unroll
      for (int ks = 0; ks < KS; ++ks) {
        short8 a0 = *(const short8*)(xa + ks * 32);
        short8 a1 = *(const short8*)(xa + (size_t)16 * KD + ks * 32);
        short8 bw = *(const short8*)(wp + ks * 32);
        acc0 = __builtin_amdgcn_mfma_f32_16x16x32_bf16(a0, bw, acc0, 0, 0, 0);
        acc1 = __builtin_amdgcn_mfma_f32_16x16x32_bf16(a1, bw, acc1, 0, 0, 0);
      }
    }
    if (t > 0) {
      // ---- poll all 32 producer seqs >= t (MALL loads, no cache ops)
      {
        const unsigned int* fp = seqg + (l & 31);
        unsigned int v; int spin = 0;
        do {
          asm volatile("global_load_dword %0, %1, off sc0 sc1\n\ts_waitcnt vmcnt(0)"
                       : "=v"(v) : "v"(fp) : "memory");
        } while (!__all((int)(v >= (unsigned)t) | ownlane) && ++spin < (1 << 14));
      }
      // ---- gather h_{t-1} from MALL, stage into Ha (frag layout)
      const unsigned short* hsrc = h_buf + (size_t)((t - 1) & 1) * 131072 + group * 16384;
      u32x4 hv[8];
      #pragma unroll
      for (int i = 0; i < 8; ++i) {
        const unsigned short* gp = hsrc + (size_t)(tid + i * 256) * 8;
        asm volatile("global_load_dwordx4 %0, %1, off sc0 sc1"
                     : "=v"(hv[i]) : "v"(gp) : "memory");
      }
      asm volatile("s_waitcnt vmcnt(0)" ::: "memory");
      __builtin_amdgcn_sched_barrier(0);
      #pragma unroll
      for (int i = 0; i < 8; ++i) {
        int g = tid + i * 256;
        int ks = g >> 7, rem = g & 127, rr = rem >> 2, cq = rem & 3;
        *(u32x4*)(Ha + ks * 2560 + rr * 80 + cq * 16) = hv[i];
      }
      __syncthreads();  // staging visible
      // ---- zh = h_{t-1} @ U-slice
      #pragma unroll
      for (int ks = 0; ks < 16; ++ks) {
        short8 bfr = *(const short8*)((char*)Uf + ((size_t)(ks * 4 + w) * 64 + l) * 16);
        short8 a0 = *(const short8*)(Ha + ks * 2560 + (l & 15) * 80 + (l >> 4) * 16);
        short8 a1 = *(const short8*)(Ha + ks * 2560 + ((l & 15) + 16) * 80 + (l >> 4) * 16);
        acc0 = __builtin_amdgcn_mfma_f32_16x16x32_bf16(a0, bfr, acc0, 0, 0, 0);
        acc1 = __builtin_amdgcn_mfma_f32_16x16x32_bf16(a1, bfr, acc1, 0, 0, 0);
      }
    }
    // ---- z exchange via LDS
    #pragma unroll
    for (int i = 0; i < 4; ++i) {
      Zl[((l >> 4) * 4 + i) * 65 + w * 16 + (l & 15)] = acc0[i];
      Zl[((l >> 4) * 4 + i + 16) * 65 + w * 16 + (l & 15)] = acc1[i];
    }
    __syncthreads();  // z visible
    // ---- gates (fp32), h
    unsigned short hb2[2];
    #pragma unroll
    for (int p = 0; p < 2; ++p) {
      int r = r0 + p * 16;
      float zi = Zl[r * 65 +      j2];
      float zf = Zl[r * 65 + 16 + j2];
      float zg = Zl[r * 65 + 32 + j2];
      float zo = Zl[r * 65 + 48 + j2];
      float ig = 1.f / (1.f + __expf(-zi));
      float fg = 1.f / (1.f + __expf(-zf));
      float gg = 1.f - 2.f / (__expf(2.f * zg) + 1.f);   // robust tanh
      float og = 1.f / (1.f + __expf(-zo));
      float c = fg * c_state[p] + ig * gg;
      c_state[p] = c;
      float th = 1.f - 2.f / (__expf(2.f * c) + 1.f);
      hb2[p] = f2bf(og * th);
    }
    // ---- publish h to MALL (write-through stores), drain, barrier, seq++
    {
      unsigned short* hd = h_buf + (size_t)(t & 1) * 131072 + hwo;
      unsigned int v0 = hb2[0], v1 = hb2[1];
      asm volatile("global_store_short %0, %1, off sc0 sc1"
                   :: "v"(hd + r0 * 32), "v"(v0) : "memory");
      asm volatile("global_store_short %0, %1, off sc0 sc1"
                   :: "v"(hd + (r0 + 16) * 32), "v"(v1) : "memory");
      asm volatile("s_waitcnt vmcnt(0)" ::: "memory");
    }
    __syncthreads();  // all threads' h at MALL; also Zl/Ha reuse fence
    if (tid == 0) {
      unsigned int nv = (unsigned int)(t + 1);
      asm volatile("global_store_dword %0, %1, off sc0 sc1"
                   :: "v"(myseq), "v"(nv) : "memory");
    }
    // ---- x_out (cached path, off the critical chain)
    x_out[((size_t)t * NB + brow0) * NH + n_] = hb2[0];
    x_out[((size_t)t * NB + brow0 + 16) * NH + n_] = hb2[1];
  }
}

// ---------------------------------------------------------------------------
extern "C" void kernel_launch(void* const* d_in, const int* in_sizes, int n_in,
                              void* d_out, int out_size, void* d_ws, size_t ws_size,
                              hipStream_t stream) {
  const int*   tokens = (const int*)  d_in[0];
  const float* emb    = (const float*)d_in[1];
  const float* w0     = (const float*)d_in[2];
  const float* u0     = (const float*)d_in[3];
  const float* b0     = (const float*)d_in[4];
  const float* w_rest = (const float*)d_in[5];
  const float* u_rest = (const float*)d_in[6];
  const float* b_rest = (const float*)d_in[7];
  const float* dw1    = (const float*)d_in[8];
  const float* db1    = (const float*)d_in[9];
  const float* dw2    = (const float*)d_in[10];
  const float* db2    = (const float*)d_in[11];
  float* out = (float*)d_out;

  char* ws = (char*)d_ws;
  size_t off = 0;
  auto alloc = [&](size_t bytes) -> char* {
    char* p = ws + off;
    off += (bytes + 255) & ~(size_t)255;
    return p;
  };
  unsigned short* ut[4];
  for (int i = 0; i < 4; ++i) ut[i] = (unsigned short*)alloc((size_t)N4H * NH * 2);
  unsigned short* w0t = (unsigned short*)alloc((size_t)N4H * NE * 2);
  unsigned short* wt[3];
  for (int i = 0; i < 3; ++i) wt[i] = (unsigned short*)alloc((size_t)N4H * NH * 2);
  unsigned short* dw1t = (unsigned short*)alloc((size_t)1024 * 512 * 2);
  unsigned short* dw2t = (unsigned short*)alloc((size_t)32 * 1024 * 2);
  unsigned short* x0  = (unsigned short*)alloc((size_t)NB * NS * NE * 2);
  unsigned short* xA  = (unsigned short*)alloc((size_t)NB * NS * NH * 2);
  unsigned short* hb  = (unsigned short*)alloc((size_t)2 * 8 * 16384 * 2);
  unsigned int*  seq  = (unsigned int*)alloc((size_t)4 * 8 * 32 * 4);

  // head intermediate chunk buffer from remaining workspace
  size_t avail = (ws_size > off) ? (ws_size - off) : 0;
  long RC = (long)(avail / ((size_t)1024 * 2));
  if (RC > (long)NB * NS) RC = (long)NB * NS;
  RC &= ~(long)127;
  if (RC < 128) RC = 128;  // should never trigger given observed ws_size
  unsigned short* h1buf = (unsigned short*)alloc((size_t)RC * 1024 * 2);

  (void)hipMemsetAsync(seq, 0, (size_t)4 * 8 * 32 * 4, stream);

  // Weight transposes (f32 [K][N] -> bf16 [N][K])
  transpose_cast<<<dim3(1, N4H), 256, 0, stream>>>(w0, w0t, NE, N4H);
  transpose_cast<<<dim3(2, N4H), 256, 0, stream>>>(u0, ut[0], NH, N4H);
  for (int i = 0; i < 3; ++i) {
    transpose_cast<<<dim3(2, N4H), 256, 0, stream>>>(w_rest + (size_t)i * NH * N4H, wt[i], NH, N4H);
    transpose_cast<<<dim3(2, N4H), 256, 0, stream>>>(u_rest + (size_t)i * NH * N4H, ut[i + 1], NH, N4H);
  }
  transpose_cast<<<dim3(2, 1024), 256, 0, stream>>>(dw1, dw1t, 512, 1024);
  transpose_cast<<<dim3(4, 32), 256, 0, stream>>>(dw2, dw2t, 1024, 32);

  embed_kernel<<<16384, 256, 0, stream>>>(tokens, emb, x0);

  (void)hipFuncSetAttribute((const void*)lstm_scan_fused<NE>,
                            hipFuncAttributeMaxDynamicSharedMemorySize, SCAN_LDS_BYTES);
  (void)hipFuncSetAttribute((const void*)lstm_scan_fused<NH>,
                            hipFuncAttributeMaxDynamicSharedMemorySize, SCAN_LDS_BYTES);

  // Layer 0: x0 -> xA ; layers 1-3: xA -> xA in place (stage t read before write)
  lstm_scan_fused<NE><<<256, 256, SCAN_LDS_BYTES, stream>>>(
      x0, w0t, ut[0], b0, xA, hb, seq);
  for (int lyr = 1; lyr < 4; ++lyr) {
    lstm_scan_fused<NH><<<256, 256, SCAN_LDS_BYTES, stream>>>(
        xA, wt[lyr - 1], ut[lyr], b_rest + (size_t)(lyr - 1) * N4H, xA, hb,
        seq + (size_t)lyr * 8 * 32);
  }

  // Dense head, row-chunked through h1buf: h1 = relu(x@dw1+db1); out = h1@dw2+db2
  for (long r0 = 0; r0 < (long)NB * NS; r0 += RC) {
    long rows = ((long)NB * NS - r0 < RC) ? ((long)NB * NS - r0) : RC;
    gemm_bt<128, 128, true, true, false, false>
        <<<dim3(1024 / 128, rows / 128), 256, 0, stream>>>(
            xA + (size_t)r0 * NH, dw1t, h1buf, db1, (int)rows, 1024, NH, 0);
    gemm_bt<128, 32, true, false, true, true>
        <<<dim3(1, rows / 128), 256, 0, stream>>>(
            h1buf, dw2t, out, db2, (int)rows, 32, 1024, (int)r0);
  }
}